// Round 16
// baseline (146.089 us; speedup 1.0000x reference)
//
#include <hip/hip_runtime.h>
#include <hip/hip_bf16.h>

#define EPS_ODIN 0.0014f

constexpr int Bb  = 1024;
constexpr int Cc  = 100;
constexpr int Dd  = 512;
constexpr int INn = 3072;
constexpr int PITCH = 68;   // shorts; 136B pitch

using s16x8 = __attribute__((ext_vector_type(8))) short;
using s16x4 = __attribute__((ext_vector_type(4))) short;
using f32x4 = __attribute__((ext_vector_type(4))) float;

__device__ __forceinline__ short f2bf(float f) {
    __hip_bfloat16 h = __float2bfloat16(f);
    return *reinterpret_cast<short*>(&h);
}

// ---------------- prep: x/invsig bf16 planes + W transpose; zero ism pad rows ----------------
// ism_b layout: rows 0..511 = invsig bf16; rows 512..611 = im bf16 (written by im_q); 612..639 = 0
__global__ __launch_bounds__(256) void prep_kernel(
    const float* __restrict__ x, const float* __restrict__ W,
    const float* __restrict__ invsig,
    short* __restrict__ x_b, short* __restrict__ Wt_b, short* __restrict__ ism_b)
{
    __shared__ float tp[32][33];
    const int tid = threadIdx.x, bid = blockIdx.x;
    const long gstride = (long)gridDim.x * 256;
    auto cvt4 = [&](const float* in, short* ob, long q) {
        long idx = q * 4;
        f32x4 v = *(const f32x4*)(in + idx);
        s16x4 o;
        #pragma unroll
        for (int j = 0; j < 4; ++j) o[j] = f2bf(v[j]);
        *(s16x4*)(ob + idx) = o;
    };
    for (long i = (long)bid * 256 + tid; i < (long)Bb * INn / 4; i += gstride) cvt4(x, x_b, i);
    for (long i = (long)bid * 256 + tid; i < (long)Dd * Dd / 4; i += gstride) cvt4(invsig, ism_b, i);
    for (long i = (long)bid * 256 + tid; i < 28 * 512 / 4; i += gstride)
        *(s16x4*)(ism_b + (long)612 * 512 + i * 4) = s16x4{0, 0, 0, 0};

    const int tx = tid & 31, ty = tid >> 5;
    for (int tix = bid; tix < (INn / 32) * (Dd / 32); tix += gridDim.x) {
        int r0 = (tix >> 4) * 32, c0 = (tix & 15) * 32;
        #pragma unroll
        for (int i2 = 0; i2 < 4; ++i2)
            tp[ty + i2 * 8][tx] = W[(long)(r0 + ty + i2 * 8) * Dd + c0 + tx];
        __syncthreads();
        #pragma unroll
        for (int i2 = 0; i2 < 4; ++i2) {
            int c = c0 + ty + i2 * 8;
            Wt_b[(long)c * INn + r0 + tx] = f2bf(tp[tx][ty + i2 * 8]);
        }
        __syncthreads();
    }
}

// ---------------- im = mu @ invsig (fp32 exact) ; q[c] = mu_c . im_c ; im bf16 -> ism rows 512+ ----------------
__global__ __launch_bounds__(256) void im_q_kernel(
    const float* __restrict__ mu, const float* __restrict__ invsig,
    float* __restrict__ im, float* __restrict__ q, short* __restrict__ ism_b)
{
    __shared__ float muc[512];
    __shared__ float red[4];
    const int tid = threadIdx.x, c = blockIdx.x;
    for (int e = tid; e < 512; e += 256) muc[e] = mu[(long)c * 512 + e];
    __syncthreads();
    const int d0 = tid, d1 = tid + 256;
    float a0 = 0.f, a1 = 0.f, a2 = 0.f, a3 = 0.f;
    for (int e = 0; e < 512; e += 2) {
        float m0 = muc[e], m1 = muc[e + 1];
        a0 = fmaf(m0, invsig[(long)e * 512 + d0], a0);
        a1 = fmaf(m0, invsig[(long)e * 512 + d1], a1);
        a2 = fmaf(m1, invsig[(long)(e + 1) * 512 + d0], a2);
        a3 = fmaf(m1, invsig[(long)(e + 1) * 512 + d1], a3);
    }
    float r0 = a0 + a2, r1 = a1 + a3;
    im[(long)c * 512 + d0] = r0;
    im[(long)c * 512 + d1] = r1;
    ism_b[(long)(512 + c) * 512 + d0] = f2bf(r0);
    ism_b[(long)(512 + c) * 512 + d1] = f2bf(r1);
    float s = muc[d0] * r0 + muc[d1] * r1;
    #pragma unroll
    for (int off = 32; off; off >>= 1) s += __shfl_down(s, off);
    if ((tid & 63) == 0) red[tid >> 6] = s;
    __syncthreads();
    if (tid == 0) q[c] = red[0] + red[1] + red[2] + red[3];
}

// ---------------- 128x64 tile GEMM body (device fn) ----------------
__device__ __forceinline__ void gemm_tile128(
    short* __restrict__ As, short* __restrict__ Bs,
    const short* __restrict__ A, const short* __restrict__ Bm,
    long K, long kbeg, int nkt, int m0, int n0, f32x4 (&acc)[2][4])
{
    const int tid = threadIdx.x;
    const int lane = tid & 63, w = tid >> 6, wm = w * 32;
    const int lrow = lane & 15, kseg = lane >> 4;
    const int srow = tid >> 3, skc = (tid & 7) * 8;

    s16x8 rA[4], rB[2];
    auto ldA = [&](int kt) {
        #pragma unroll
        for (int i = 0; i < 4; ++i)
            rA[i] = *(const s16x8*)(A + (long)(m0 + srow + i * 32) * K + kbeg + (long)kt * 64 + skc);
    };
    auto ldB = [&](int kt) {
        #pragma unroll
        for (int i = 0; i < 2; ++i)
            rB[i] = *(const s16x8*)(Bm + (long)(n0 + srow + i * 32) * K + kbeg + (long)kt * 64 + skc);
    };

    ldA(0); ldB(0);
    for (int kt = 0; kt < nkt; ++kt) {
        #pragma unroll
        for (int i = 0; i < 4; ++i)
            *(s16x8*)&As[(srow + i * 32) * PITCH + skc] = rA[i];
        #pragma unroll
        for (int i = 0; i < 2; ++i)
            *(s16x8*)&Bs[(srow + i * 32) * PITCH + skc] = rB[i];
        __syncthreads();
        if (kt + 1 < nkt) { ldA(kt + 1); ldB(kt + 1); }
        #pragma unroll
        for (int kk = 0; kk < 2; ++kk) {
            s16x8 ah[2], bfr[4];
            #pragma unroll
            for (int i = 0; i < 2; ++i)
                ah[i] = *(const s16x8*)&As[(wm + i * 16 + lrow) * PITCH + kk * 32 + kseg * 8];
            #pragma unroll
            for (int j = 0; j < 4; ++j)
                bfr[j] = *(const s16x8*)&Bs[(j * 16 + lrow) * PITCH + kk * 32 + kseg * 8];
            #pragma unroll
            for (int i = 0; i < 2; ++i)
                #pragma unroll
                for (int j = 0; j < 4; ++j)
                    acc[i][j] = __builtin_amdgcn_mfma_f32_16x16x32_bf16(ah[i], bfr[j], acc[i][j], 0, 0, 0);
        }
        __syncthreads();
    }
}

// ---------------- merged partials, single call site: WtW (0..127) + feat (128..383), split-K4 ----------------
// Class-uniform: K=INn, nkt=12, B=Wt_b, store stride 512. Branch only sets {A, m0, dst}.
__global__ __launch_bounds__(256, 4) void partials2(
    const short* __restrict__ x_b, const short* __restrict__ Wt_b,
    float* __restrict__ wpart, float* __restrict__ part)
{
    __shared__ short As[128 * PITCH];
    __shared__ short Bs[64 * PITCH];
    const int bid = blockIdx.x, tid = threadIdx.x;
    const int lane = tid & 63, w = tid >> 6, wm = w * 32;
    const int crow = (lane >> 4) * 4, ccol = lane & 15;

    const short* A;
    int m0, n0;
    float* dst;
    long kbeg;
    if (bid < 128) {
        int z = bid >> 5, rem = bid & 31;
        A = Wt_b; m0 = (rem >> 3) * 128; n0 = (rem & 7) * 64;
        dst = wpart + (long)z * Dd * Dd;
        kbeg = (long)z * 768;
    } else {
        int idx = bid - 128, z = idx >> 6, rem = idx & 63;
        A = x_b; m0 = (rem >> 3) * 128; n0 = (rem & 7) * 64;
        dst = part + (long)z * Bb * Dd;
        kbeg = (long)z * 768;
    }

    f32x4 acc[2][4];
    #pragma unroll
    for (int i = 0; i < 2; ++i)
        #pragma unroll
        for (int j = 0; j < 4; ++j)
            acc[i][j] = f32x4{0.f, 0.f, 0.f, 0.f};

    gemm_tile128(As, Bs, A, Wt_b, INn, kbeg, 12, m0, n0, acc);

    #pragma unroll
    for (int i = 0; i < 2; ++i)
        #pragma unroll
        for (int j = 0; j < 4; ++j)
            #pragma unroll
            for (int r = 0; r < 4; ++r)
                dst[(long)(m0 + wm + i * 16 + crow + r) * 512 + n0 + j * 16 + ccol] = acc[i][j][r];
}

// ---------------- feat2 GEMM (K=512): feat2 = relu(featpre + bias + esc*dz@WtW) -> fp32 + bf16 ----------------
__global__ __launch_bounds__(256, 4) void gemm_feat2(
    const short* __restrict__ A, const short* __restrict__ Bm,
    float* __restrict__ Cm,
    const float* __restrict__ aux1, const float* __restrict__ aux2,
    short* __restrict__ obf, float esc)
{
    __shared__ short As[128 * PITCH];
    __shared__ short Bs[64 * PITCH];
    const int tid = threadIdx.x;
    const int m0 = blockIdx.y * 128, n0 = blockIdx.x * 64;
    const int lane = tid & 63, w = tid >> 6, wm = w * 32;

    f32x4 acc[2][4];
    #pragma unroll
    for (int i = 0; i < 2; ++i)
        #pragma unroll
        for (int j = 0; j < 4; ++j)
            acc[i][j] = f32x4{0.f, 0.f, 0.f, 0.f};

    gemm_tile128(As, Bs, A, Bm, 512, 0, 8, m0, n0, acc);

    const int crow = (lane >> 4) * 4, ccol = lane & 15;
    #pragma unroll
    for (int i = 0; i < 2; ++i)
        #pragma unroll
        for (int j = 0; j < 4; ++j)
            #pragma unroll
            for (int r = 0; r < 4; ++r) {
                int gm = m0 + wm + i * 16 + crow + r;
                int gn = n0 + j * 16 + ccol;
                long cidx = (long)gm * 512 + gn;
                float u = fmaxf(aux1[cidx] + aux2[gn] + esc * acc[i][j][r], 0.f);
                Cm[cidx] = u;
                obf[cidx] = f2bf(u);
            }
}

// ---------------- merged h|t GEMM: A[1024,512] @ ism^T[640,512] ----------------
__global__ __launch_bounds__(256, 4) void gemm_ht(
    const short* __restrict__ A, const short* __restrict__ Bm,
    float* __restrict__ hbuf, float* __restrict__ tbuf)
{
    __shared__ short As[128 * PITCH];
    __shared__ short Bs[64 * PITCH];
    const int tid = threadIdx.x;
    const int m0 = blockIdx.y * 128, n0 = blockIdx.x * 64;
    const int lane = tid & 63, w = tid >> 6, wm = w * 32;

    f32x4 acc[2][4];
    #pragma unroll
    for (int i = 0; i < 2; ++i)
        #pragma unroll
        for (int j = 0; j < 4; ++j)
            acc[i][j] = f32x4{0.f, 0.f, 0.f, 0.f};

    gemm_tile128(As, Bs, A, Bm, 512, 0, 8, m0, n0, acc);

    const int crow = (lane >> 4) * 4, ccol = lane & 15;
    if (n0 < 512) {
        #pragma unroll
        for (int i = 0; i < 2; ++i)
            #pragma unroll
            for (int j = 0; j < 4; ++j)
                #pragma unroll
                for (int r = 0; r < 4; ++r)
                    hbuf[(long)(m0 + wm + i * 16 + crow + r) * 512 + n0 + j * 16 + ccol] = acc[i][j][r];
    } else {
        #pragma unroll
        for (int i = 0; i < 2; ++i)
            #pragma unroll
            for (int j = 0; j < 4; ++j)
                #pragma unroll
                for (int r = 0; r < 4; ++r)
                    tbuf[(long)(m0 + wm + i * 16 + crow + r) * 128 + (n0 - 512) + j * 16 + ccol] = acc[i][j][r];
    }
}

// ---------------- reduce 4 split-K slabs + bias + relu -> featpre, feat fp32 + bf16 ----------------
__global__ __launch_bounds__(256) void reduce_feat(
    const float* __restrict__ part, const float* __restrict__ bias,
    float* __restrict__ featpre, float* __restrict__ feat, short* __restrict__ fb)
{
    long idx = ((long)blockIdx.x * 256 + threadIdx.x) * 4;
    f32x4 v = *(const f32x4*)(part + idx);
    #pragma unroll
    for (int z = 1; z < 4; ++z)
        v += *(const f32x4*)(part + (long)z * Bb * Dd + idx);
    *(f32x4*)(featpre + idx) = v;
    f32x4 bb = *(const f32x4*)(bias + (idx & 511));
    s16x4 o;
    #pragma unroll
    for (int j = 0; j < 4; ++j) {
        v[j] = fmaxf(v[j] + bb[j], 0.f);
        o[j] = f2bf(v[j]);
    }
    *(f32x4*)(feat + idx) = v;
    *(s16x4*)(fb + idx) = o;
}

// ---------------- reduce 4 WtW slabs -> bf16 ----------------
__global__ __launch_bounds__(256) void reduce_wtw(
    const float* __restrict__ wpart, short* __restrict__ wtw_b)
{
    long idx = ((long)blockIdx.x * 256 + threadIdx.x) * 4;
    f32x4 v = *(const f32x4*)(wpart + idx);
    #pragma unroll
    for (int z = 1; z < 4; ++z)
        v += *(const f32x4*)(wpart + (long)z * Dd * Dd + idx);
    s16x4 o;
    #pragma unroll
    for (int j = 0; j < 4; ++j) o[j] = f2bf(v[j]);
    *(s16x4*)(wtw_b + idx) = o;
}

// ---------------- tail A2: argmax(2t-q) per row -> dz = -2(h-im[c*])*(feat>0) ----------------
__global__ __launch_bounds__(256) void tail_a2(
    const float* __restrict__ tbuf, const float* __restrict__ q,
    const float* __restrict__ feat, const float* __restrict__ hbuf,
    const float* __restrict__ im, short* __restrict__ dz_b)
{
    __shared__ int cstv[4];
    const int tid = threadIdx.x, lane = tid & 63, w = tid >> 6;
    const int m0 = blockIdx.x * 4;

    {
        const float* tr = tbuf + (long)(m0 + w) * 128;
        float best = 2.f * tr[lane] - q[lane];
        int bestc = lane;
        if (lane + 64 < 100) {
            float v1 = 2.f * tr[lane + 64] - q[lane + 64];
            if (v1 > best) { best = v1; bestc = lane + 64; }
        }
        #pragma unroll
        for (int mk = 1; mk <= 32; mk <<= 1) {
            float ov = __shfl_xor(best, mk);
            int   oc = __shfl_xor(bestc, mk);
            if (ov > best || (ov == best && oc < bestc)) { best = ov; bestc = oc; }
        }
        if (lane == 0) cstv[w] = bestc;
    }
    __syncthreads();

    #pragma unroll
    for (int it = 0; it < 2; ++it) {
        int i4 = it * 256 + tid;
        int r = i4 >> 7, d4 = (i4 & 127) * 4;
        long gi = (long)(m0 + r) * 512 + d4;
        f32x4 fv = *(const f32x4*)(feat + gi);
        f32x4 hv = *(const f32x4*)(hbuf + gi);
        f32x4 iv = *(const f32x4*)(im + (long)cstv[r] * 512 + d4);
        s16x4 o;
        #pragma unroll
        for (int jj = 0; jj < 4; ++jj) {
            float v = (fv[jj] > 0.f) ? -2.f * (hv[jj] - iv[jj]) : 0.f;
            o[jj] = f2bf(v);
        }
        *(s16x4*)(dz_b + gi) = o;
    }
}

// ---------------- tail B2: s = feat2 . h2 per row ; out = 2*t2 - s - q ----------------
__global__ __launch_bounds__(256) void tail_b2(
    const float* __restrict__ tbuf, const float* __restrict__ q,
    const float* __restrict__ feat, const float* __restrict__ hbuf,
    float* __restrict__ out)
{
    __shared__ float srow[4];
    const int tid = threadIdx.x, lane = tid & 63, w = tid >> 6;
    const int m0 = blockIdx.x * 4;

    {
        long gi = (long)(m0 + w) * 512 + lane * 8;
        f32x4 a0 = *(const f32x4*)(feat + gi);
        f32x4 a1 = *(const f32x4*)(feat + gi + 4);
        f32x4 b0 = *(const f32x4*)(hbuf + gi);
        f32x4 b1 = *(const f32x4*)(hbuf + gi + 4);
        float ss = 0.f;
        #pragma unroll
        for (int jj = 0; jj < 4; ++jj) ss += a0[jj] * b0[jj] + a1[jj] * b1[jj];
        #pragma unroll
        for (int off = 32; off; off >>= 1) ss += __shfl_down(ss, off);
        if (lane == 0) srow[w] = ss;
    }
    __syncthreads();

    #pragma unroll
    for (int it = 0; it < 2; ++it) {
        int i = it * 256 + tid;
        if (i < 400) {
            int r = i / 100, c = i - r * 100;
            out[(long)(m0 + r) * 100 + c] = 2.f * tbuf[(long)(m0 + r) * 128 + c] - srow[r] - q[c];
        }
    }
}

extern "C" void kernel_launch(void* const* d_in, const int* in_sizes, int n_in,
                              void* d_out, int out_size, void* d_ws, size_t ws_size,
                              hipStream_t stream)
{
    const float* x      = (const float*)d_in[0];
    const float* W      = (const float*)d_in[1];
    const float* bias   = (const float*)d_in[2];
    const float* mu     = (const float*)d_in[3];
    const float* invsig = (const float*)d_in[4];
    float* out = (float*)d_out;

    char* wp = (char*)d_ws;
    auto alloc = [&](size_t bytes) { char* p = wp; wp += (bytes + 255) & ~size_t(255); return p; };
    short* x_b   = (short*)alloc((size_t)Bb * INn * 2);
    short* Wt_b  = (short*)alloc((size_t)Dd * INn * 2);
    short* ism_b = (short*)alloc((size_t)640 * Dd * 2);   // [invsig | im | pad]
    short* wtw_b = (short*)alloc((size_t)Dd * Dd * 2);
    float* im    = (float*)alloc((size_t)Cc * Dd * 4);
    float* q     = (float*)alloc(512);
    float* part  = (float*)alloc((size_t)4 * Bb * Dd * 4);
    float* wpart = (float*)alloc((size_t)4 * Dd * Dd * 4);
    float* featpre = (float*)alloc((size_t)Bb * Dd * 4);
    float* feat  = (float*)alloc((size_t)Bb * Dd * 4);
    short* f_b   = (short*)alloc((size_t)Bb * Dd * 2);
    float* hbuf  = (float*)alloc((size_t)Bb * Dd * 4);
    float* tbuf  = (float*)alloc((size_t)Bb * 128 * 4);
    short* dz_b  = (short*)alloc((size_t)Bb * Dd * 2);

    dim3 blk(256);

    // 1. bf16 planes + W transpose (+ ism pad zeroing)
    prep_kernel<<<512, blk, 0, stream>>>(x, W, invsig, x_b, Wt_b, ism_b);
    // 2. im (fp32 exact) + q + im bf16 into ism rows 512..611
    im_q_kernel<<<Cc, blk, 0, stream>>>(mu, invsig, im, q, ism_b);
    // 3. merged partials: WtW (128 blk) + x@W (256 blk), single call site, split-K4
    partials2<<<384, blk, 0, stream>>>(x_b, Wt_b, wpart, part);
    // 4. reduce WtW -> bf16
    reduce_wtw<<<256, blk, 0, stream>>>(wpart, wtw_b);
    // 5. reduce feat + bias + relu -> featpre, feat, f_b
    reduce_feat<<<512, blk, 0, stream>>>(part, bias, featpre, feat, f_b);
    // 6. h|t = feat @ [invsig | im^T]  (80 blocks)
    gemm_ht<<<dim3(10, 8), blk, 0, stream>>>(f_b, ism_b, hbuf, tbuf);
    // 7. argmax + dz (elementwise, 256 blocks)
    tail_a2<<<Bb / 4, blk, 0, stream>>>(tbuf, q, feat, hbuf, im, dz_b);
    // 8. feat2 = relu(featpre + bias + eps * dz@WtW)   [linearized FGSM]
    gemm_feat2<<<dim3(8, 8), blk, 0, stream>>>(dz_b, wtw_b, feat, featpre, bias, f_b, EPS_ODIN);
    // 9. h2|t2 = feat2 @ [invsig | im^T]  (80 blocks)
    gemm_ht<<<dim3(10, 8), blk, 0, stream>>>(f_b, ism_b, hbuf, tbuf);
    // 10. s + out (elementwise, 256 blocks)
    tail_b2<<<Bb / 4, blk, 0, stream>>>(tbuf, q, feat, hbuf, out);
}

// Round 17
// 99.802 us; speedup vs baseline: 1.4638x; 1.4638x over previous
//
#include <hip/hip_runtime.h>
#include <hip/hip_bf16.h>

#define EPS_ODIN 0.0014f

constexpr int Bb  = 1024;
constexpr int Cc  = 100;
constexpr int Dd  = 512;
constexpr int INn = 3072;
constexpr int PITCH = 68;   // shorts; 136B pitch

using s16x8 = __attribute__((ext_vector_type(8))) short;
using s16x4 = __attribute__((ext_vector_type(4))) short;
using f32x4 = __attribute__((ext_vector_type(4))) float;

__device__ __forceinline__ short f2bf(float f) {
    __hip_bfloat16 h = __float2bfloat16(f);
    return *reinterpret_cast<short*>(&h);
}

// ---------------- prep: x/invsig bf16 planes + W transpose; zero ism pad rows ----------------
// ism_b layout: rows 0..511 = invsig bf16; rows 512..611 = im bf16 (written by im_q); 612..639 = 0
__global__ __launch_bounds__(256) void prep_kernel(
    const float* __restrict__ x, const float* __restrict__ W,
    const float* __restrict__ invsig,
    short* __restrict__ x_b, short* __restrict__ Wt_b, short* __restrict__ ism_b)
{
    __shared__ float tp[32][33];
    const int tid = threadIdx.x, bid = blockIdx.x;
    const long gstride = (long)gridDim.x * 256;
    auto cvt4 = [&](const float* in, short* ob, long q) {
        long idx = q * 4;
        f32x4 v = *(const f32x4*)(in + idx);
        s16x4 o;
        #pragma unroll
        for (int j = 0; j < 4; ++j) o[j] = f2bf(v[j]);
        *(s16x4*)(ob + idx) = o;
    };
    for (long i = (long)bid * 256 + tid; i < (long)Bb * INn / 4; i += gstride) cvt4(x, x_b, i);
    for (long i = (long)bid * 256 + tid; i < (long)Dd * Dd / 4; i += gstride) cvt4(invsig, ism_b, i);
    for (long i = (long)bid * 256 + tid; i < 28 * 512 / 4; i += gstride)
        *(s16x4*)(ism_b + (long)612 * 512 + i * 4) = s16x4{0, 0, 0, 0};

    const int tx = tid & 31, ty = tid >> 5;
    for (int tix = bid; tix < (INn / 32) * (Dd / 32); tix += gridDim.x) {
        int r0 = (tix >> 4) * 32, c0 = (tix & 15) * 32;
        #pragma unroll
        for (int i2 = 0; i2 < 4; ++i2)
            tp[ty + i2 * 8][tx] = W[(long)(r0 + ty + i2 * 8) * Dd + c0 + tx];
        __syncthreads();
        #pragma unroll
        for (int i2 = 0; i2 < 4; ++i2) {
            int c = c0 + ty + i2 * 8;
            Wt_b[(long)c * INn + r0 + tx] = f2bf(tp[tx][ty + i2 * 8]);
        }
        __syncthreads();
    }
}

// ---------------- im = mu @ invsig (fp32 exact) ; q[c] = mu_c . im_c ; im bf16 -> ism rows 512+ ----------------
__global__ __launch_bounds__(256) void im_q_kernel(
    const float* __restrict__ mu, const float* __restrict__ invsig,
    float* __restrict__ im, float* __restrict__ q, short* __restrict__ ism_b)
{
    __shared__ float muc[512];
    __shared__ float red[4];
    const int tid = threadIdx.x, c = blockIdx.x;
    for (int e = tid; e < 512; e += 256) muc[e] = mu[(long)c * 512 + e];
    __syncthreads();
    const int d0 = tid, d1 = tid + 256;
    float a0 = 0.f, a1 = 0.f, a2 = 0.f, a3 = 0.f;
    for (int e = 0; e < 512; e += 2) {
        float m0 = muc[e], m1 = muc[e + 1];
        a0 = fmaf(m0, invsig[(long)e * 512 + d0], a0);
        a1 = fmaf(m0, invsig[(long)e * 512 + d1], a1);
        a2 = fmaf(m1, invsig[(long)(e + 1) * 512 + d0], a2);
        a3 = fmaf(m1, invsig[(long)(e + 1) * 512 + d1], a3);
    }
    float r0 = a0 + a2, r1 = a1 + a3;
    im[(long)c * 512 + d0] = r0;
    im[(long)c * 512 + d1] = r1;
    ism_b[(long)(512 + c) * 512 + d0] = f2bf(r0);
    ism_b[(long)(512 + c) * 512 + d1] = f2bf(r1);
    float s = muc[d0] * r0 + muc[d1] * r1;
    #pragma unroll
    for (int off = 32; off; off >>= 1) s += __shfl_down(s, off);
    if ((tid & 63) == 0) red[tid >> 6] = s;
    __syncthreads();
    if (tid == 0) q[c] = red[0] + red[1] + red[2] + red[3];
}

// ---------------- single-plane bf16 GEMM, 128x64 tile, BK=64 ----------------
// EPI 0 -> partial slab (z, stride sstr); 3 -> feat2 = relu(aux1+aux2[n]+esc*acc) -> Cm + obf
template<int EPI>
__global__ __launch_bounds__(256, 4) void gemm_b1(
    const short* __restrict__ A, const short* __restrict__ Bm,
    float* __restrict__ Cm, long K, int kcount, int N, long sstr,
    const float* __restrict__ aux1, const float* __restrict__ aux2,
    short* __restrict__ obf, float esc)
{
    __shared__ short As[128 * PITCH];
    __shared__ short Bs[64 * PITCH];
    const int tid = threadIdx.x;
    const int m0 = blockIdx.y * 128, n0 = blockIdx.x * 64;
    const long kbeg = (long)blockIdx.z * kcount;
    const int lane = tid & 63, w = tid >> 6, wm = w * 32;
    const int lrow = lane & 15, kseg = lane >> 4;
    const int srow = tid >> 3, skc = (tid & 7) * 8;
    const int nkt = kcount >> 6;

    f32x4 acc[2][4];
    #pragma unroll
    for (int i = 0; i < 2; ++i)
        #pragma unroll
        for (int j = 0; j < 4; ++j)
            acc[i][j] = f32x4{0.f, 0.f, 0.f, 0.f};

    s16x8 rA[4], rB[2];
    auto ldA = [&](int kt) {
        #pragma unroll
        for (int i = 0; i < 4; ++i)
            rA[i] = *(const s16x8*)(A + (long)(m0 + srow + i * 32) * K + kbeg + (long)kt * 64 + skc);
    };
    auto ldB = [&](int kt) {
        #pragma unroll
        for (int i = 0; i < 2; ++i)
            rB[i] = *(const s16x8*)(Bm + (long)(n0 + srow + i * 32) * K + kbeg + (long)kt * 64 + skc);
    };

    ldA(0); ldB(0);
    for (int kt = 0; kt < nkt; ++kt) {
        #pragma unroll
        for (int i = 0; i < 4; ++i)
            *(s16x8*)&As[(srow + i * 32) * PITCH + skc] = rA[i];
        #pragma unroll
        for (int i = 0; i < 2; ++i)
            *(s16x8*)&Bs[(srow + i * 32) * PITCH + skc] = rB[i];
        __syncthreads();
        if (kt + 1 < nkt) { ldA(kt + 1); ldB(kt + 1); }
        #pragma unroll
        for (int kk = 0; kk < 2; ++kk) {
            s16x8 ah[2], bfr[4];
            #pragma unroll
            for (int i = 0; i < 2; ++i)
                ah[i] = *(const s16x8*)&As[(wm + i * 16 + lrow) * PITCH + kk * 32 + kseg * 8];
            #pragma unroll
            for (int j = 0; j < 4; ++j)
                bfr[j] = *(const s16x8*)&Bs[(j * 16 + lrow) * PITCH + kk * 32 + kseg * 8];
            #pragma unroll
            for (int i = 0; i < 2; ++i)
                #pragma unroll
                for (int j = 0; j < 4; ++j)
                    acc[i][j] = __builtin_amdgcn_mfma_f32_16x16x32_bf16(ah[i], bfr[j], acc[i][j], 0, 0, 0);
        }
        __syncthreads();
    }

    const int crow = (lane >> 4) * 4, ccol = lane & 15;
    #pragma unroll
    for (int i = 0; i < 2; ++i)
        #pragma unroll
        for (int j = 0; j < 4; ++j)
            #pragma unroll
            for (int r = 0; r < 4; ++r) {
                int gm = m0 + wm + i * 16 + crow + r;
                int gn = n0 + j * 16 + ccol;
                float v = acc[i][j][r];
                if (EPI == 0) {
                    (Cm + (long)blockIdx.z * sstr)[(long)gm * 512 + gn] = v;
                } else {
                    long cidx = (long)gm * N + gn;
                    float u = fmaxf(aux1[cidx] + aux2[gn] + esc * v, 0.f);
                    Cm[cidx] = u;
                    obf[cidx] = f2bf(u);
                }
            }
}

// ---------------- merged h|t GEMM: A[1024,512] @ ism^T[640,512] ----------------
// n0 < 512 -> hbuf fp32 [1024,512]; n0 >= 512 -> tbuf fp32 [1024,128]
__global__ __launch_bounds__(256, 4) void gemm_ht(
    const short* __restrict__ A, const short* __restrict__ Bm,
    float* __restrict__ hbuf, float* __restrict__ tbuf)
{
    __shared__ short As[128 * PITCH];
    __shared__ short Bs[64 * PITCH];
    const int tid = threadIdx.x;
    const int m0 = blockIdx.y * 128, n0 = blockIdx.x * 64;
    const int lane = tid & 63, w = tid >> 6, wm = w * 32;
    const int lrow = lane & 15, kseg = lane >> 4;
    const int srow = tid >> 3, skc = (tid & 7) * 8;

    f32x4 acc[2][4];
    #pragma unroll
    for (int i = 0; i < 2; ++i)
        #pragma unroll
        for (int j = 0; j < 4; ++j)
            acc[i][j] = f32x4{0.f, 0.f, 0.f, 0.f};

    s16x8 rA[4], rB[2];
    auto ldA = [&](int kt) {
        #pragma unroll
        for (int i = 0; i < 4; ++i)
            rA[i] = *(const s16x8*)(A + (long)(m0 + srow + i * 32) * 512 + kt * 64 + skc);
    };
    auto ldB = [&](int kt) {
        #pragma unroll
        for (int i = 0; i < 2; ++i)
            rB[i] = *(const s16x8*)(Bm + (long)(n0 + srow + i * 32) * 512 + kt * 64 + skc);
    };

    ldA(0); ldB(0);
    for (int kt = 0; kt < 8; ++kt) {
        #pragma unroll
        for (int i = 0; i < 4; ++i)
            *(s16x8*)&As[(srow + i * 32) * PITCH + skc] = rA[i];
        #pragma unroll
        for (int i = 0; i < 2; ++i)
            *(s16x8*)&Bs[(srow + i * 32) * PITCH + skc] = rB[i];
        __syncthreads();
        if (kt + 1 < 8) { ldA(kt + 1); ldB(kt + 1); }
        #pragma unroll
        for (int kk = 0; kk < 2; ++kk) {
            s16x8 ah[2], bfr[4];
            #pragma unroll
            for (int i = 0; i < 2; ++i)
                ah[i] = *(const s16x8*)&As[(wm + i * 16 + lrow) * PITCH + kk * 32 + kseg * 8];
            #pragma unroll
            for (int j = 0; j < 4; ++j)
                bfr[j] = *(const s16x8*)&Bs[(j * 16 + lrow) * PITCH + kk * 32 + kseg * 8];
            #pragma unroll
            for (int i = 0; i < 2; ++i)
                #pragma unroll
                for (int j = 0; j < 4; ++j)
                    acc[i][j] = __builtin_amdgcn_mfma_f32_16x16x32_bf16(ah[i], bfr[j], acc[i][j], 0, 0, 0);
        }
        __syncthreads();
    }

    const int crow = (lane >> 4) * 4, ccol = lane & 15;
    if (n0 < 512) {
        #pragma unroll
        for (int i = 0; i < 2; ++i)
            #pragma unroll
            for (int j = 0; j < 4; ++j)
                #pragma unroll
                for (int r = 0; r < 4; ++r)
                    hbuf[(long)(m0 + wm + i * 16 + crow + r) * 512 + n0 + j * 16 + ccol] = acc[i][j][r];
    } else {
        #pragma unroll
        for (int i = 0; i < 2; ++i)
            #pragma unroll
            for (int j = 0; j < 4; ++j)
                #pragma unroll
                for (int r = 0; r < 4; ++r)
                    tbuf[(long)(m0 + wm + i * 16 + crow + r) * 128 + (n0 - 512) + j * 16 + ccol] = acc[i][j][r];
    }
}

// ---------------- reduce 4 split-K slabs + bias + relu -> featpre, feat fp32 + bf16 ----------------
__global__ __launch_bounds__(256) void reduce_feat(
    const float* __restrict__ part, const float* __restrict__ bias,
    float* __restrict__ featpre, float* __restrict__ feat, short* __restrict__ fb)
{
    long idx = ((long)blockIdx.x * 256 + threadIdx.x) * 4;
    f32x4 v = *(const f32x4*)(part + idx);
    #pragma unroll
    for (int z = 1; z < 4; ++z)
        v += *(const f32x4*)(part + (long)z * Bb * Dd + idx);
    *(f32x4*)(featpre + idx) = v;
    f32x4 bb = *(const f32x4*)(bias + (idx & 511));
    s16x4 o;
    #pragma unroll
    for (int j = 0; j < 4; ++j) {
        v[j] = fmaxf(v[j] + bb[j], 0.f);
        o[j] = f2bf(v[j]);
    }
    *(f32x4*)(feat + idx) = v;
    *(s16x4*)(fb + idx) = o;
}

// ---------------- reduce 4 WtW slabs -> bf16 ----------------
__global__ __launch_bounds__(256) void reduce_wtw(
    const float* __restrict__ wpart, short* __restrict__ wtw_b)
{
    long idx = ((long)blockIdx.x * 256 + threadIdx.x) * 4;
    f32x4 v = *(const f32x4*)(wpart + idx);
    #pragma unroll
    for (int z = 1; z < 4; ++z)
        v += *(const f32x4*)(wpart + (long)z * Dd * Dd + idx);
    s16x4 o;
    #pragma unroll
    for (int j = 0; j < 4; ++j) o[j] = f2bf(v[j]);
    *(s16x4*)(wtw_b + idx) = o;
}

// ---------------- tail A2: argmax(2t-q) per row -> dz = -2(h-im[c*])*(feat>0) ----------------
__global__ __launch_bounds__(256) void tail_a2(
    const float* __restrict__ tbuf, const float* __restrict__ q,
    const float* __restrict__ feat, const float* __restrict__ hbuf,
    const float* __restrict__ im, short* __restrict__ dz_b)
{
    __shared__ int cstv[4];
    const int tid = threadIdx.x, lane = tid & 63, w = tid >> 6;
    const int m0 = blockIdx.x * 4;

    {
        const float* tr = tbuf + (long)(m0 + w) * 128;
        float best = 2.f * tr[lane] - q[lane];
        int bestc = lane;
        if (lane + 64 < 100) {
            float v1 = 2.f * tr[lane + 64] - q[lane + 64];
            if (v1 > best) { best = v1; bestc = lane + 64; }
        }
        #pragma unroll
        for (int mk = 1; mk <= 32; mk <<= 1) {
            float ov = __shfl_xor(best, mk);
            int   oc = __shfl_xor(bestc, mk);
            if (ov > best || (ov == best && oc < bestc)) { best = ov; bestc = oc; }
        }
        if (lane == 0) cstv[w] = bestc;
    }
    __syncthreads();

    #pragma unroll
    for (int it = 0; it < 2; ++it) {
        int i4 = it * 256 + tid;
        int r = i4 >> 7, d4 = (i4 & 127) * 4;
        long gi = (long)(m0 + r) * 512 + d4;
        f32x4 fv = *(const f32x4*)(feat + gi);
        f32x4 hv = *(const f32x4*)(hbuf + gi);
        f32x4 iv = *(const f32x4*)(im + (long)cstv[r] * 512 + d4);
        s16x4 o;
        #pragma unroll
        for (int jj = 0; jj < 4; ++jj) {
            float v = (fv[jj] > 0.f) ? -2.f * (hv[jj] - iv[jj]) : 0.f;
            o[jj] = f2bf(v);
        }
        *(s16x4*)(dz_b + gi) = o;
    }
}

// ---------------- tail B2: s = feat2 . h2 per row ; out = 2*t2 - s - q ----------------
__global__ __launch_bounds__(256) void tail_b2(
    const float* __restrict__ tbuf, const float* __restrict__ q,
    const float* __restrict__ feat, const float* __restrict__ hbuf,
    float* __restrict__ out)
{
    __shared__ float srow[4];
    const int tid = threadIdx.x, lane = tid & 63, w = tid >> 6;
    const int m0 = blockIdx.x * 4;

    {
        long gi = (long)(m0 + w) * 512 + lane * 8;
        f32x4 a0 = *(const f32x4*)(feat + gi);
        f32x4 a1 = *(const f32x4*)(feat + gi + 4);
        f32x4 b0 = *(const f32x4*)(hbuf + gi);
        f32x4 b1 = *(const f32x4*)(hbuf + gi + 4);
        float ss = 0.f;
        #pragma unroll
        for (int jj = 0; jj < 4; ++jj) ss += a0[jj] * b0[jj] + a1[jj] * b1[jj];
        #pragma unroll
        for (int off = 32; off; off >>= 1) ss += __shfl_down(ss, off);
        if (lane == 0) srow[w] = ss;
    }
    __syncthreads();

    #pragma unroll
    for (int it = 0; it < 2; ++it) {
        int i = it * 256 + tid;
        if (i < 400) {
            int r = i / 100, c = i - r * 100;
            out[(long)(m0 + r) * 100 + c] = 2.f * tbuf[(long)(m0 + r) * 128 + c] - srow[r] - q[c];
        }
    }
}

extern "C" void kernel_launch(void* const* d_in, const int* in_sizes, int n_in,
                              void* d_out, int out_size, void* d_ws, size_t ws_size,
                              hipStream_t stream)
{
    const float* x      = (const float*)d_in[0];
    const float* W      = (const float*)d_in[1];
    const float* bias   = (const float*)d_in[2];
    const float* mu     = (const float*)d_in[3];
    const float* invsig = (const float*)d_in[4];
    float* out = (float*)d_out;

    char* wp = (char*)d_ws;
    auto alloc = [&](size_t bytes) { char* p = wp; wp += (bytes + 255) & ~size_t(255); return p; };
    short* x_b   = (short*)alloc((size_t)Bb * INn * 2);
    short* Wt_b  = (short*)alloc((size_t)Dd * INn * 2);
    short* ism_b = (short*)alloc((size_t)640 * Dd * 2);   // [invsig | im | pad]
    short* wtw_b = (short*)alloc((size_t)Dd * Dd * 2);
    float* im    = (float*)alloc((size_t)Cc * Dd * 4);
    float* q     = (float*)alloc(512);
    float* part  = (float*)alloc((size_t)4 * Bb * Dd * 4);
    float* wpart = (float*)alloc((size_t)4 * Dd * Dd * 4);
    float* featpre = (float*)alloc((size_t)Bb * Dd * 4);
    float* feat  = (float*)alloc((size_t)Bb * Dd * 4);
    short* f_b   = (short*)alloc((size_t)Bb * Dd * 2);
    float* hbuf  = (float*)alloc((size_t)Bb * Dd * 4);
    float* tbuf  = (float*)alloc((size_t)Bb * 128 * 4);
    short* dz_b  = (short*)alloc((size_t)Bb * Dd * 2);

    dim3 blk(256);

    // 1. bf16 planes + W transpose (+ ism pad zeroing)
    prep_kernel<<<512, blk, 0, stream>>>(x, W, invsig, x_b, Wt_b, ism_b);
    // 2. im (fp32 exact) + q + im bf16 into ism rows 512..611
    im_q_kernel<<<Cc, blk, 0, stream>>>(mu, invsig, im, q, ism_b);
    // 3. WtW partials: Wt@Wt^T split-K4 (128 blocks)
    gemm_b1<0><<<dim3(8, 4, 4), blk, 0, stream>>>(
        Wt_b, Wt_b, wpart, INn, INn / 4, Dd, (long)Dd * Dd, nullptr, nullptr, nullptr, 0.f);
    // 4. reduce WtW -> bf16
    reduce_wtw<<<256, blk, 0, stream>>>(wpart, wtw_b);
    // 5. feat partials: x@W split-K4 (256 blocks)
    gemm_b1<0><<<dim3(8, 8, 4), blk, 0, stream>>>(
        x_b, Wt_b, part, INn, INn / 4, Dd, (long)Bb * Dd, nullptr, nullptr, nullptr, 0.f);
    // 6. reduce feat + bias + relu -> featpre, feat, f_b
    reduce_feat<<<512, blk, 0, stream>>>(part, bias, featpre, feat, f_b);
    // 7. h|t = feat @ [invsig | im^T]  (80 blocks)
    gemm_ht<<<dim3(10, 8), blk, 0, stream>>>(f_b, ism_b, hbuf, tbuf);
    // 8. argmax + dz (elementwise, 256 blocks)
    tail_a2<<<Bb / 4, blk, 0, stream>>>(tbuf, q, feat, hbuf, im, dz_b);
    // 9. feat2 = relu(featpre + bias + eps * dz@WtW)   [linearized FGSM]
    gemm_b1<3><<<dim3(8, 8), blk, 0, stream>>>(
        dz_b, wtw_b, feat, Dd, Dd, Dd, 0, featpre, bias, f_b, EPS_ODIN);
    // 10. h2|t2 = feat2 @ [invsig | im^T]  (80 blocks)
    gemm_ht<<<dim3(10, 8), blk, 0, stream>>>(f_b, ism_b, hbuf, tbuf);
    // 11. s + out (elementwise, 256 blocks)
    tail_b2<<<Bb / 4, blk, 0, stream>>>(tbuf, q, feat, hbuf, out);
}